// Round 11
// baseline (196.217 us; speedup 1.0000x reference)
//
#include <hip/hip_runtime.h>
#include <cmath>

typedef _Float16 f16;
typedef _Float16 f16x8 __attribute__((ext_vector_type(8)));
typedef float    f32x4 __attribute__((ext_vector_type(4)));
typedef unsigned short u16;
typedef unsigned int   u32;
typedef unsigned long long u64;
typedef u16 us8 __attribute__((ext_vector_type(8)));
typedef u16 us4 __attribute__((ext_vector_type(4)));

#define MFMA16(a, b, c) __builtin_amdgcn_mfma_f32_16x16x32_f16((a), (b), (c), 0, 0, 0)

__device__ __forceinline__ void gload_lds16(const void* g, void* l) {
    __builtin_amdgcn_global_load_lds((const __attribute__((address_space(1))) void*)g,
                                     (__attribute__((address_space(3))) void*)l, 16, 0, 0);
}

// ---------------- cast f32->f16 (weights only) -----------------------------------
__global__ void castk(const float* __restrict__ src, f16* __restrict__ dst, int n8) {
    int i = blockIdx.x * 256 + threadIdx.x;
    if (i >= n8) return;
    const float4* s = (const float4*)src + (size_t)i * 2;
    float4 a = s[0], b = s[1];
    union { f16 h[8]; us8 v; } o;
    o.h[0] = (f16)a.x; o.h[1] = (f16)a.y; o.h[2] = (f16)a.z; o.h[3] = (f16)a.w;
    o.h[4] = (f16)b.x; o.h[5] = (f16)b.y; o.h[6] = (f16)b.z; o.h[7] = (f16)b.w;
    *(us8*)&dst[(size_t)i * 8] = o.v;
}

// ---------------- prep: O f32 -> Of16 (straight) + OT (transposed), one O read ---
__global__ void prep(const float* __restrict__ O, f16* __restrict__ Of16,
                     f16* __restrict__ OT) {
    __shared__ f16 tbuf[64][68];
    int bid = blockIdx.x;
    int b = bid >> 8, t = bid & 255;
    int s0 = (t & 31) * 64, h0 = (t >> 5) * 64;
    const float* Ob = O + (size_t)b * 2048 * 512;
    f16* Ofb = Of16 + (size_t)b * 2048 * 512;
    f16* OTb = OT + (size_t)b * 512 * 2048;
    int tid = threadIdx.x;
    int rr = tid >> 4, cc = (tid & 15) * 4;
#pragma unroll
    for (int i = 0; i < 4; ++i) {
        int r = rr + 16 * i;
        float4 v = *(const float4*)&Ob[(size_t)(s0 + r) * 512 + h0 + cc];
        union { f16 h[4]; us4 u; } st;
        st.h[0] = (f16)v.x; st.h[1] = (f16)v.y; st.h[2] = (f16)v.z; st.h[3] = (f16)v.w;
        *(us4*)&Ofb[(size_t)(s0 + r) * 512 + h0 + cc] = st.u;
        tbuf[r][cc + 0] = st.h[0]; tbuf[r][cc + 1] = st.h[1];
        tbuf[r][cc + 2] = st.h[2]; tbuf[r][cc + 3] = st.h[3];
    }
    __syncthreads();
#pragma unroll
    for (int i = 0; i < 4; ++i) {
        int hr = rr + 16 * i;
        union { f16 h[4]; us4 v; } pk;
        pk.h[0] = tbuf[cc + 0][hr]; pk.h[1] = tbuf[cc + 1][hr];
        pk.h[2] = tbuf[cc + 2][hr]; pk.h[3] = tbuf[cc + 3][hr];
        *(us4*)&OTb[(size_t)(h0 + hr) * 2048 + s0 + cc] = pk.v;
    }
}

// ---------------- GEMM1: Qf16 = tanh(Of16 * Wf16^T + bias) ----------------------
__global__ __launch_bounds__(256) void gemm1(const f16* __restrict__ A,
                                             const f16* __restrict__ W,
                                             const float* __restrict__ bias,
                                             f16* __restrict__ Qo) {
    __shared__ f16 lA[128 * 32];
    __shared__ f16 lB[128 * 32];
    const int tid = threadIdx.x;
    const int lane = tid & 63, w = tid >> 6;
    const int wm = w >> 1, wn = w & 1;
    const int bm = blockIdx.x >> 2, bn = blockIdx.x & 3;
    const int r0 = bm * 128, c0 = bn * 128;
    const int l15 = lane & 15, g = lane >> 4;
    f32x4 acc[4][4] = {};
    for (int kt = 0; kt < 16; ++kt) {
        int k0 = kt * 32;
        __syncthreads();
#pragma unroll
        for (int i = 0; i < 2; ++i) {
            int slot = i * 256 + tid;
            int row = slot >> 2, oct = slot & 3;
            int soct = oct ^ (row & 3);
            *(us8*)&lA[slot * 8] = *(const us8*)&A[(size_t)(r0 + row) * 512 + k0 + soct * 8];
            *(us8*)&lB[slot * 8] = *(const us8*)&W[(size_t)(c0 + row) * 512 + k0 + soct * 8];
        }
        __syncthreads();
        f16x8 af[4], bf[4];
#pragma unroll
        for (int mf = 0; mf < 4; ++mf) {
            int row = 64 * wm + 16 * mf + l15;
            int oct = g ^ (row & 3);
            af[mf] = *(const f16x8*)&lA[(row * 4 + oct) * 8];
        }
#pragma unroll
        for (int nf = 0; nf < 4; ++nf) {
            int row = 64 * wn + 16 * nf + l15;
            int oct = g ^ (row & 3);
            bf[nf] = *(const f16x8*)&lB[(row * 4 + oct) * 8];
        }
#pragma unroll
        for (int mf = 0; mf < 4; ++mf)
#pragma unroll
            for (int nf = 0; nf < 4; ++nf)
                acc[mf][nf] = MFMA16(af[mf], bf[nf], acc[mf][nf]);
    }
    float bv[4];
#pragma unroll
    for (int nf = 0; nf < 4; ++nf) bv[nf] = bias[c0 + 64 * wn + 16 * nf + l15];
#pragma unroll
    for (int mf = 0; mf < 4; ++mf) {
#pragma unroll
        for (int nf = 0; nf < 4; ++nf) {
#pragma unroll
            for (int r = 0; r < 4; ++r) {
                float y = tanhf(acc[mf][nf][r] + bv[nf]);
                int row = r0 + 64 * wm + 16 * mf + 4 * g + r;
                int col = c0 + 64 * wn + 16 * nf + l15;
                Qo[(size_t)row * 512 + col] = (f16)y;
            }
        }
    }
}

// ---------------- fused attention, t-split + P-through-LDS PV -------------------
// Grid 256: b = blk&7 (XCD-pinned), tt = (blk>>3)&1, qt = blk>>4 (QBLK=128).
// 512 threads = 8 waves. Phase 1 (per wave, own 16q): QK^T + online softmax
// (always-rescale) -> write P(f16, swizzled) + corr to LDS. Phase 2 (per wave,
// own 64-h slice, ALL 128q): PV with 4 V-frags (reused over 8 q-tiles) + 8 P-frags
// -> 44 LDS reads/wave-iter vs R10's 64. K/V double-buffered via global_load_lds,
// vmcnt(8) steady. Partials: tt=0 raw f32 -> P0; tt=1 normalized f16 -> P1.
__global__ __launch_bounds__(512, 1) void attn(const f16* __restrict__ Qf,
                                               const f16* __restrict__ Of,
                                               const f16* __restrict__ OfT,
                                               float* __restrict__ P0,
                                               f16* __restrict__ P1,
                                               float* __restrict__ ML) {
    extern __shared__ __align__(16) char smem[];  // 140288 bytes
    // K dbuf @0 (2x32K) | V dbuf @65536 (2x32K) | P @131072 (8K) | corr @139264 | linv @139776
    f16*   lP    = (f16*)(smem + 131072);
    float* lcorr = (float*)(smem + 139264);
    float* linv  = (float*)(smem + 139776);
    const int tid = threadIdx.x;
    const int lane = tid & 63, w = tid >> 6;
    const int l15 = lane & 15, g = lane >> 4;
    const int b = blockIdx.x & 7, tt = (blockIdx.x >> 3) & 1, qt = blockIdx.x >> 4;
    const int q0 = qt * 128;
    const int tb = tt * 1024;
    const f16* Ob  = Of  + (size_t)b * 2048 * 512;
    const f16* OTb = OfT + (size_t)b * 512 * 2048;

    // Q B-fragments: q = q0 + 16w + l15, k = 32ks + 8g + j
    f16x8 qf[16];
    const f16* qrow = Qf + ((size_t)b * 2048 + q0 + 16 * w + l15) * 512;
#pragma unroll
    for (int ks = 0; ks < 16; ++ks) qf[ks] = *(const f16x8*)&qrow[ks * 32 + g * 8];

    float m = -INFINITY, lsum = 0.f;
    f32x4 acc[4][8] = {};  // [hf: 16h within 64-h slice][qfi: 16q tile]

    const int pkey = (l15 >> 1) & 3;                 // P granule swizzle key
    const int kx = (l15 & 3) ^ ((l15 >> 2) & 3);     // V granule swizzle key
    const int go = g ^ kx;
    const int qloc = 16 * w + l15;

    auto STAGE_K = [&](int buf, int t0) {
        f16* dst = (f16*)(smem + buf * 32768);
#pragma unroll
        for (int i = 0; i < 4; ++i) {
            int slot = i * 512 + tid;
            int t = slot >> 6, oct = slot & 63;
            gload_lds16(&Ob[(size_t)(t0 + t) * 512 + 8 * (oct ^ (t & 7))], &dst[slot * 8]);
        }
    };
    auto STAGE_V = [&](int buf, int t0) {
        f16* dst = (f16*)(smem + 65536 + buf * 32768);
#pragma unroll
        for (int i = 0; i < 4; ++i) {
            int slot = i * 512 + tid;
            int h = slot >> 2, gr = slot & 3;
            int key = (h & 3) ^ ((h >> 2) & 3);
            gload_lds16(&OTb[(size_t)h * 2048 + t0 + 8 * (gr ^ key)], &dst[slot * 8]);
        }
    };

    STAGE_K(0, tb);
    STAGE_V(0, tb);

    for (int kt = 0; kt < 32; ++kt) {
        const int cur = kt & 1;
        const f16* lK = (const f16*)(smem + cur * 32768);
        const f16* lV = (const f16*)(smem + 65536 + cur * 32768);

        if (kt < 31) {
            STAGE_K(cur ^ 1, tb + (kt + 1) * 32);
            STAGE_V(cur ^ 1, tb + (kt + 1) * 32);
            asm volatile("s_waitcnt vmcnt(8)" ::: "memory");  // K/V[kt] landed
        } else {
            asm volatile("s_waitcnt vmcnt(0)" ::: "memory");
        }
        __builtin_amdgcn_s_barrier();

        // ---- phase 1: QK^T S^T[32t][16q] (q = l15, t = 16mf+4g+r) ----
        f32x4 sa[2] = {};
#pragma unroll
        for (int ks = 0; ks < 16; ++ks) {
#pragma unroll
            for (int mf = 0; mf < 2; ++mf) {
                int t = 16 * mf + l15;
                int oct = (4 * ks + g) ^ (t & 7);
                f16x8 kf = *(const f16x8*)&lK[(t * 64 + oct) * 8];
                sa[mf] = MFMA16(kf, qf[ks], sa[mf]);
            }
        }

        // ---- online softmax, always-rescale ----
        float tmax = -INFINITY;
#pragma unroll
        for (int mf = 0; mf < 2; ++mf)
#pragma unroll
            for (int r = 0; r < 4; ++r) tmax = fmaxf(tmax, sa[mf][r]);
        tmax = fmaxf(tmax, __shfl_xor(tmax, 16));
        tmax = fmaxf(tmax, __shfl_xor(tmax, 32));
        float mnew = fmaxf(m, tmax);
        float corr = __expf(m - mnew);
        m = mnew;
        float p[2][4];
        float ps = 0.f;
#pragma unroll
        for (int mf = 0; mf < 2; ++mf)
#pragma unroll
            for (int r = 0; r < 4; ++r) { p[mf][r] = __expf(sa[mf][r] - m); ps += p[mf][r]; }
        ps += __shfl_xor(ps, 16);
        ps += __shfl_xor(ps, 32);
        lsum = lsum * corr + ps;
        if (g == 0) lcorr[qloc] = corr;

        // ---- P write: row q (64B), granule (t/8) swizzled by pkey ----
        union { f16 h[4]; u64 u; } pk0, pk1;
#pragma unroll
        for (int r = 0; r < 4; ++r) { pk0.h[r] = (f16)p[0][r]; pk1.h[r] = (f16)p[1][r]; }
        *(u64*)((char*)lP + qloc * 64 + 16 * (((g >> 1)    ) ^ pkey) + 8 * (g & 1)) = pk0.u;
        *(u64*)((char*)lP + qloc * 64 + 16 * (((g >> 1) + 2) ^ pkey) + 8 * (g & 1)) = pk1.u;

        asm volatile("s_waitcnt lgkmcnt(0)" ::: "memory");
        __builtin_amdgcn_s_barrier();   // all P/corr visible

        // ---- phase 2: PV for h-slice 64w..64w+63, all 128 q ----
        f16x8 vf[4];
#pragma unroll
        for (int hf = 0; hf < 4; ++hf) {
            int h = 64 * w + 16 * hf + l15;
            vf[hf] = *(const f16x8*)&lV[(h * 4 + go) * 8];
        }
#pragma unroll
        for (int qfi = 0; qfi < 8; ++qfi) {
            float c = lcorr[16 * qfi + l15];
            f16x8 pf = *(const f16x8*)((const char*)lP + (16 * qfi + l15) * 64 + 16 * (g ^ pkey));
#pragma unroll
            for (int hf = 0; hf < 4; ++hf) {
                acc[hf][qfi] *= c;
                acc[hf][qfi] = MFMA16(vf[hf], pf, acc[hf][qfi]);
            }
        }

        asm volatile("s_waitcnt lgkmcnt(0)" ::: "memory");
        __builtin_amdgcn_s_barrier();   // all reads done -> buffers reusable
    }

    // ---- epilogue ----
    if (g == 0) {
        const size_t mrow = (size_t)tt * 16384 + (size_t)b * 2048 + q0 + qloc;
        ML[mrow * 2 + 0] = m;
        ML[mrow * 2 + 1] = lsum;
        linv[qloc] = 1.0f / lsum;
    }
    __syncthreads();
    if (tt == 0) {
#pragma unroll
        for (int qfi = 0; qfi < 8; ++qfi) {
            const size_t row = (size_t)b * 2048 + q0 + 16 * qfi + l15;
#pragma unroll
            for (int hf = 0; hf < 4; ++hf) {
                float4 o;
                o.x = acc[hf][qfi][0]; o.y = acc[hf][qfi][1];
                o.z = acc[hf][qfi][2]; o.w = acc[hf][qfi][3];
                *(float4*)&P0[row * 512 + 64 * w + 16 * hf + 4 * g] = o;
            }
        }
    } else {
#pragma unroll
        for (int qfi = 0; qfi < 8; ++qfi) {
            const size_t row = (size_t)b * 2048 + q0 + 16 * qfi + l15;
            float inv = linv[16 * qfi + l15];
#pragma unroll
            for (int hf = 0; hf < 4; ++hf) {
                union { f16 h[4]; us4 v; } pk;
                pk.h[0] = (f16)(acc[hf][qfi][0] * inv); pk.h[1] = (f16)(acc[hf][qfi][1] * inv);
                pk.h[2] = (f16)(acc[hf][qfi][2] * inv); pk.h[3] = (f16)(acc[hf][qfi][3] * inv);
                *(us4*)&P1[row * 512 + 64 * w + 16 * hf + 4 * g] = pk.v;
            }
        }
    }
}

// ---------------- merge: out = (e0*P0 + e1*l1*P1n) / (e0*l0 + e1*l1) -------------
__global__ __launch_bounds__(256) void merge_k(float* __restrict__ P0,
                                               const f16* __restrict__ P1,
                                               const float* __restrict__ ML) {
    const int tid = threadIdx.x;
    const size_t row = (size_t)blockIdx.x * 8 + (tid >> 5);
    const int c = (tid & 31) * 16;
    float m0 = ML[row * 2 + 0], l0 = ML[row * 2 + 1];
    float m1 = ML[(16384 + row) * 2 + 0], l1 = ML[(16384 + row) * 2 + 1];
    float M = fmaxf(m0, m1);
    float e0 = __expf(m0 - M), e1 = __expf(m1 - M);
    float w1 = e1 * l1;
    float inv = 1.0f / (e0 * l0 + w1);
    float a0 = e0 * inv, a1 = w1 * inv;
#pragma unroll
    for (int j = 0; j < 4; ++j) {
        size_t off = row * 512 + c + 4 * j;
        float4 v0 = *(const float4*)&P0[off];
        us4 v1u = *(const us4*)&P1[off];
        const f16* v1 = (const f16*)&v1u;
        float4 o;
        o.x = a0 * v0.x + a1 * (float)v1[0];
        o.y = a0 * v0.y + a1 * (float)v1[1];
        o.z = a0 * v0.z + a1 * (float)v1[2];
        o.w = a0 * v0.w + a1 * (float)v1[3];
        *(float4*)&P0[off] = o;
    }
}

extern "C" void kernel_launch(void* const* d_in, const int* in_sizes, int n_in,
                              void* d_out, int out_size, void* d_ws, size_t ws_size,
                              hipStream_t stream) {
    const float* O  = (const float*)d_in[0];
    const float* Ww = (const float*)d_in[1];
    const float* Wb = (const float*)d_in[2];
    float* Out = (float*)d_out;
    char* ws = (char*)d_ws;
    f16* Of16 = (f16*)ws;                           // 16 MB
    f16* OT   = (f16*)(ws + ((size_t)16 << 20));    // 16 MB
    f16* Qf   = (f16*)(ws + ((size_t)32 << 20));    // 16 MB
    f16* Wf   = (f16*)(ws + ((size_t)48 << 20));    // 512 KB
    f16* P1   = (f16*)(ws + ((size_t)49 << 20));    // 16 MB (normalized f16 partial)
    float* ML = (float*)(ws + ((size_t)65 << 20));  // 512 KB (m, lsum per row per tt)

    hipFuncSetAttribute((const void*)attn, hipFuncAttributeMaxDynamicSharedMemorySize, 140288);

    prep<<<2048, 256, 0, stream>>>(O, Of16, OT);
    castk<<<128, 256, 0, stream>>>(Ww, Wf, 32768);
    gemm1<<<512, 256, 0, stream>>>(Of16, Wf, Wb, Qf);
    attn<<<256, 512, 140288, stream>>>(Qf, Of16, OT, Out, P1, ML);
    merge_k<<<2048, 256, 0, stream>>>(Out, P1, ML);
}

// Round 12
// 170.021 us; speedup vs baseline: 1.1541x; 1.1541x over previous
//
#include <hip/hip_runtime.h>
#include <cmath>

typedef _Float16 f16;
typedef _Float16 f16x8 __attribute__((ext_vector_type(8)));
typedef float    f32x4 __attribute__((ext_vector_type(4)));
typedef unsigned short u16;
typedef unsigned int   u32;
typedef u16 us8 __attribute__((ext_vector_type(8)));
typedef u16 us4 __attribute__((ext_vector_type(4)));

#define MFMA16(a, b, c) __builtin_amdgcn_mfma_f32_16x16x32_f16((a), (b), (c), 0, 0, 0)

__device__ __forceinline__ void gload_lds16(const void* g, void* l) {
    __builtin_amdgcn_global_load_lds((const __attribute__((address_space(1))) void*)g,
                                     (__attribute__((address_space(3))) void*)l, 16, 0, 0);
}

// ---------------- cast f32->f16 (weights only) -----------------------------------
__global__ void castk(const float* __restrict__ src, f16* __restrict__ dst, int n8) {
    int i = blockIdx.x * 256 + threadIdx.x;
    if (i >= n8) return;
    const float4* s = (const float4*)src + (size_t)i * 2;
    float4 a = s[0], b = s[1];
    union { f16 h[8]; us8 v; } o;
    o.h[0] = (f16)a.x; o.h[1] = (f16)a.y; o.h[2] = (f16)a.z; o.h[3] = (f16)a.w;
    o.h[4] = (f16)b.x; o.h[5] = (f16)b.y; o.h[6] = (f16)b.z; o.h[7] = (f16)b.w;
    *(us8*)&dst[(size_t)i * 8] = o.v;
}

// ---------------- prep: O f32 -> Of16 (straight) + OT (transposed), one O read ---
__global__ void prep(const float* __restrict__ O, f16* __restrict__ Of16,
                     f16* __restrict__ OT) {
    __shared__ f16 tbuf[64][68];
    int bid = blockIdx.x;
    int b = bid >> 8, t = bid & 255;
    int s0 = (t & 31) * 64, h0 = (t >> 5) * 64;
    const float* Ob = O + (size_t)b * 2048 * 512;
    f16* Ofb = Of16 + (size_t)b * 2048 * 512;
    f16* OTb = OT + (size_t)b * 512 * 2048;
    int tid = threadIdx.x;
    int rr = tid >> 4, cc = (tid & 15) * 4;
#pragma unroll
    for (int i = 0; i < 4; ++i) {
        int r = rr + 16 * i;
        float4 v = *(const float4*)&Ob[(size_t)(s0 + r) * 512 + h0 + cc];
        union { f16 h[4]; us4 u; } st;
        st.h[0] = (f16)v.x; st.h[1] = (f16)v.y; st.h[2] = (f16)v.z; st.h[3] = (f16)v.w;
        *(us4*)&Ofb[(size_t)(s0 + r) * 512 + h0 + cc] = st.u;
        tbuf[r][cc + 0] = st.h[0]; tbuf[r][cc + 1] = st.h[1];
        tbuf[r][cc + 2] = st.h[2]; tbuf[r][cc + 3] = st.h[3];
    }
    __syncthreads();
#pragma unroll
    for (int i = 0; i < 4; ++i) {
        int hr = rr + 16 * i;
        union { f16 h[4]; us4 v; } pk;
        pk.h[0] = tbuf[cc + 0][hr]; pk.h[1] = tbuf[cc + 1][hr];
        pk.h[2] = tbuf[cc + 2][hr]; pk.h[3] = tbuf[cc + 3][hr];
        *(us4*)&OTb[(size_t)(h0 + hr) * 2048 + s0 + cc] = pk.v;
    }
}

// ---------------- GEMM1: Qf16 = tanh(Of16 * Wf16^T + bias) ----------------------
__global__ __launch_bounds__(256) void gemm1(const f16* __restrict__ A,
                                             const f16* __restrict__ W,
                                             const float* __restrict__ bias,
                                             f16* __restrict__ Qo) {
    __shared__ f16 lA[128 * 32];
    __shared__ f16 lB[128 * 32];
    const int tid = threadIdx.x;
    const int lane = tid & 63, w = tid >> 6;
    const int wm = w >> 1, wn = w & 1;
    const int bm = blockIdx.x >> 2, bn = blockIdx.x & 3;
    const int r0 = bm * 128, c0 = bn * 128;
    const int l15 = lane & 15, g = lane >> 4;
    f32x4 acc[4][4] = {};
    for (int kt = 0; kt < 16; ++kt) {
        int k0 = kt * 32;
        __syncthreads();
#pragma unroll
        for (int i = 0; i < 2; ++i) {
            int slot = i * 256 + tid;
            int row = slot >> 2, oct = slot & 3;
            int soct = oct ^ (row & 3);
            *(us8*)&lA[slot * 8] = *(const us8*)&A[(size_t)(r0 + row) * 512 + k0 + soct * 8];
            *(us8*)&lB[slot * 8] = *(const us8*)&W[(size_t)(c0 + row) * 512 + k0 + soct * 8];
        }
        __syncthreads();
        f16x8 af[4], bf[4];
#pragma unroll
        for (int mf = 0; mf < 4; ++mf) {
            int row = 64 * wm + 16 * mf + l15;
            int oct = g ^ (row & 3);
            af[mf] = *(const f16x8*)&lA[(row * 4 + oct) * 8];
        }
#pragma unroll
        for (int nf = 0; nf < 4; ++nf) {
            int row = 64 * wn + 16 * nf + l15;
            int oct = g ^ (row & 3);
            bf[nf] = *(const f16x8*)&lB[(row * 4 + oct) * 8];
        }
#pragma unroll
        for (int mf = 0; mf < 4; ++mf)
#pragma unroll
            for (int nf = 0; nf < 4; ++nf)
                acc[mf][nf] = MFMA16(af[mf], bf[nf], acc[mf][nf]);
    }
    float bv[4];
#pragma unroll
    for (int nf = 0; nf < 4; ++nf) bv[nf] = bias[c0 + 64 * wn + 16 * nf + l15];
#pragma unroll
    for (int mf = 0; mf < 4; ++mf) {
#pragma unroll
        for (int nf = 0; nf < 4; ++nf) {
#pragma unroll
            for (int r = 0; r < 4; ++r) {
                float y = tanhf(acc[mf][nf][r] + bv[nf]);
                int row = r0 + 64 * wm + 16 * mf + 4 * g + r;
                int col = c0 + 64 * wn + 16 * nf + l15;
                Qo[(size_t)row * 512 + col] = (f16)y;
            }
        }
    }
}

// ---------------- fused attention, t-split + double-buffered pipeline ------------
// (R10-verified kernel, byte-for-byte: 133.9 us, VGPR 128 + 128 AGPR, no spill.)
// Grid 256: b = blk&7 (XCD-pinned), tt = (blk>>3)&1 (t-half), qt = blk>>4 (QBLK=128).
// 512 threads = 8 waves; wave w owns 16 unique q. LDS 128KB: K dbuf + V dbuf.
// Pipeline: issue K/V[i+1] -> vmcnt(8) -> barrier -> QKT+softmax+repack+PV ->
// lgkmcnt(0) -> barrier. Partials: tt=0 raw f32 -> P0; tt=1 normalized f16 -> P1.
__global__ __launch_bounds__(512, 2) void attn(const f16* __restrict__ Qf,
                                               const f16* __restrict__ Of,
                                               const f16* __restrict__ OfT,
                                               float* __restrict__ P0,
                                               f16* __restrict__ P1,
                                               float* __restrict__ ML) {
    extern __shared__ __align__(16) char smem[];  // 131072
    const int tid = threadIdx.x;
    const int lane = tid & 63, w = tid >> 6;
    const int l15 = lane & 15, g = lane >> 4;
    const int b = blockIdx.x & 7, tt = (blockIdx.x >> 3) & 1, qt = blockIdx.x >> 4;
    const int q0 = qt * 128;
    const int tb = tt * 1024;
    const f16* Ob  = Of  + (size_t)b * 2048 * 512;
    const f16* OTb = OfT + (size_t)b * 512 * 2048;

    // Q B-fragments: q = q0 + 16w + l15, k = 32ks + 8g + j
    f16x8 qf[16];
    const f16* qrow = Qf + ((size_t)b * 2048 + q0 + 16 * w + l15) * 512;
#pragma unroll
    for (int ks = 0; ks < 16; ++ks) qf[ks] = *(const f16x8*)&qrow[ks * 32 + g * 8];

    float m = -INFINITY, lsum = 0.f;
    f32x4 acc[32] = {};

    const int addrA = 4 * (32 * (g & 1) + l15);
    const int addrB = addrA + 64;
    const int kx = (l15 & 3) ^ ((l15 >> 2) & 3);
    const int go = g ^ kx;

    // K tile [32t][512k], octet swizzle oct^(t&7); 2048 granules / 512 thr = 4 loads
    auto STAGE_K = [&](int buf, int t0) {
        f16* dst = (f16*)(smem + buf * 32768);
#pragma unroll
        for (int i = 0; i < 4; ++i) {
            int slot = i * 512 + tid;
            int t = slot >> 6, oct = slot & 63;
            gload_lds16(&Ob[(size_t)(t0 + t) * 512 + 8 * (oct ^ (t & 7))], &dst[slot * 8]);
        }
    };
    // V^T tile [512h][32t], granule swizzle gr ^ (h&3)^((h>>2)&3); 4 loads/thread
    auto STAGE_V = [&](int buf, int t0) {
        f16* dst = (f16*)(smem + 65536 + buf * 32768);
#pragma unroll
        for (int i = 0; i < 4; ++i) {
            int slot = i * 512 + tid;
            int h = slot >> 2, gr = slot & 3;
            int key = (h & 3) ^ ((h >> 2) & 3);
            gload_lds16(&OTb[(size_t)h * 2048 + t0 + 8 * (gr ^ key)], &dst[slot * 8]);
        }
    };

    STAGE_K(0, tb);
    STAGE_V(0, tb);

    for (int kt = 0; kt < 32; ++kt) {
        const int cur = kt & 1;
        const f16* lK = (const f16*)(smem + cur * 32768);
        const f16* lV = (const f16*)(smem + 65536 + cur * 32768);

        // prefetch next tile into the other buffer (its readers passed last barrier)
        if (kt < 31) {
            STAGE_K(cur ^ 1, tb + (kt + 1) * 32);
            STAGE_V(cur ^ 1, tb + (kt + 1) * 32);
            asm volatile("s_waitcnt vmcnt(8)" ::: "memory");  // K/V[kt] landed (mine)
        } else {
            asm volatile("s_waitcnt vmcnt(0)" ::: "memory");
        }
        __builtin_amdgcn_s_barrier();                         // => all waves' landed

        // ---- QK^T: S^T[32 t][16 q] ----
        f32x4 sa[2] = {};
#pragma unroll
        for (int ks = 0; ks < 16; ++ks) {
#pragma unroll
            for (int mf = 0; mf < 2; ++mf) {
                int t = 16 * mf + l15;
                int oct = (4 * ks + g) ^ (t & 7);
                f16x8 kf = *(const f16x8*)&lK[(t * 64 + oct) * 8];
                sa[mf] = MFMA16(kf, qf[ks], sa[mf]);
            }
        }

        // ---- online softmax (defer-max THR=8) ----
        float tmax = -INFINITY;
#pragma unroll
        for (int mf = 0; mf < 2; ++mf)
#pragma unroll
            for (int r = 0; r < 4; ++r) tmax = fmaxf(tmax, sa[mf][r]);
        tmax = fmaxf(tmax, __shfl_xor(tmax, 16));
        tmax = fmaxf(tmax, __shfl_xor(tmax, 32));
        if (__any(tmax > m + 8.0f)) {
            float mnew = fmaxf(m, tmax);
            float corr = __expf(m - mnew);
            m = mnew;
            lsum *= corr;
#pragma unroll
            for (int hf = 0; hf < 32; ++hf) acc[hf] *= corr;
        }
        float p[2][4];
        float ps = 0.f;
#pragma unroll
        for (int mf = 0; mf < 2; ++mf)
#pragma unroll
            for (int r = 0; r < 4; ++r) { p[mf][r] = __expf(sa[mf][r] - m); ps += p[mf][r]; }
        ps += __shfl_xor(ps, 16);
        ps += __shfl_xor(ps, 32);
        lsum += ps;

        // ---- pack P to f16, repack to B-frag via bpermute ----
        u32 Wd[2][2];
#pragma unroll
        for (int mf = 0; mf < 2; ++mf)
#pragma unroll
            for (int c = 0; c < 2; ++c) {
                union { f16 h[2]; u32 u; } x;
                x.h[0] = (f16)p[mf][2 * c]; x.h[1] = (f16)p[mf][2 * c + 1];
                Wd[mf][c] = x.u;
            }
        u32 word[4];
#pragma unroll
        for (int pp = 0; pp < 4; ++pp) {
            int adr = (pp >> 1) ? addrB : addrA;
            int w0 = __builtin_amdgcn_ds_bpermute(adr, (int)Wd[0][pp & 1]);
            int w1 = __builtin_amdgcn_ds_bpermute(adr, (int)Wd[1][pp & 1]);
            word[pp] = (lane >= 32) ? (u32)w1 : (u32)w0;
        }
        union { u32 u[4]; f16x8 v; } pkk;
        pkk.u[0] = word[0]; pkk.u[1] = word[1]; pkk.u[2] = word[2]; pkk.u[3] = word[3];
        f16x8 pfrag = pkk.v;

        // ---- PV over full 512 h ----
#pragma unroll
        for (int hf = 0; hf < 32; ++hf) {
            int h = 16 * hf + l15;
            f16x8 vf = *(const f16x8*)&lV[(h * 4 + go) * 8];
            acc[hf] = MFMA16(vf, pfrag, acc[hf]);
        }

        asm volatile("s_waitcnt lgkmcnt(0)" ::: "memory");
        __builtin_amdgcn_s_barrier();   // buffers [cur] reusable for kt+2
    }

    // ---- epilogue: write partial + (m, lsum) ----
    const size_t row = (size_t)b * 2048 + q0 + 16 * w + l15;
    if (g == 0) {
        ML[(tt * 16384 + row) * 2 + 0] = m;
        ML[(tt * 16384 + row) * 2 + 1] = lsum;
    }
    if (tt == 0) {
#pragma unroll
        for (int hf = 0; hf < 32; ++hf) {
            float4 o;
            o.x = acc[hf][0]; o.y = acc[hf][1];
            o.z = acc[hf][2]; o.w = acc[hf][3];
            *(float4*)&P0[row * 512 + 16 * hf + 4 * g] = o;
        }
    } else {
        float inv = 1.0f / lsum;
#pragma unroll
        for (int hf = 0; hf < 32; ++hf) {
            union { f16 h[4]; us4 v; } pk;
            pk.h[0] = (f16)(acc[hf][0] * inv); pk.h[1] = (f16)(acc[hf][1] * inv);
            pk.h[2] = (f16)(acc[hf][2] * inv); pk.h[3] = (f16)(acc[hf][3] * inv);
            *(us4*)&P1[row * 512 + 16 * hf + 4 * g] = pk.v;
        }
    }
}

// ---------------- merge: out = (e0*P0 + e1*l1*P1n) / (e0*l0 + e1*l1) -------------
__global__ __launch_bounds__(256) void merge_k(float* __restrict__ P0,
                                               const f16* __restrict__ P1,
                                               const float* __restrict__ ML) {
    const int tid = threadIdx.x;
    const size_t row = (size_t)blockIdx.x * 8 + (tid >> 5);
    const int c = (tid & 31) * 16;
    float m0 = ML[row * 2 + 0], l0 = ML[row * 2 + 1];
    float m1 = ML[(16384 + row) * 2 + 0], l1 = ML[(16384 + row) * 2 + 1];
    float M = fmaxf(m0, m1);
    float e0 = __expf(m0 - M), e1 = __expf(m1 - M);
    float w1 = e1 * l1;
    float inv = 1.0f / (e0 * l0 + w1);
    float a0 = e0 * inv, a1 = w1 * inv;
#pragma unroll
    for (int j = 0; j < 4; ++j) {
        size_t off = row * 512 + c + 4 * j;
        float4 v0 = *(const float4*)&P0[off];
        us4 v1u = *(const us4*)&P1[off];
        const f16* v1 = (const f16*)&v1u;
        float4 o;
        o.x = a0 * v0.x + a1 * (float)v1[0];
        o.y = a0 * v0.y + a1 * (float)v1[1];
        o.z = a0 * v0.z + a1 * (float)v1[2];
        o.w = a0 * v0.w + a1 * (float)v1[3];
        *(float4*)&P0[off] = o;
    }
}

extern "C" void kernel_launch(void* const* d_in, const int* in_sizes, int n_in,
                              void* d_out, int out_size, void* d_ws, size_t ws_size,
                              hipStream_t stream) {
    const float* O  = (const float*)d_in[0];
    const float* Ww = (const float*)d_in[1];
    const float* Wb = (const float*)d_in[2];
    float* Out = (float*)d_out;
    char* ws = (char*)d_ws;
    f16* Of16 = (f16*)ws;                           // 16 MB
    f16* OT   = (f16*)(ws + ((size_t)16 << 20));    // 16 MB
    f16* Qf   = (f16*)(ws + ((size_t)32 << 20));    // 16 MB
    f16* Wf   = (f16*)(ws + ((size_t)48 << 20));    // 512 KB
    f16* P1   = (f16*)(ws + ((size_t)49 << 20));    // 16 MB (normalized f16 partial)
    float* ML = (float*)(ws + ((size_t)65 << 20));  // 512 KB (m, lsum per row per tt)

    hipFuncSetAttribute((const void*)attn, hipFuncAttributeMaxDynamicSharedMemorySize, 131072);

    prep<<<2048, 256, 0, stream>>>(O, Of16, OT);
    castk<<<128, 256, 0, stream>>>(Ww, Wf, 32768);
    gemm1<<<512, 256, 0, stream>>>(Of16, Wf, Wb, Qf);
    attn<<<256, 512, 131072, stream>>>(Qf, Of16, OT, Out, P1, ML);
    merge_k<<<2048, 256, 0, stream>>>(Out, P1, ML);
}

// Round 14
// 167.936 us; speedup vs baseline: 1.1684x; 1.0124x over previous
//
#include <hip/hip_runtime.h>
#include <cmath>

typedef _Float16 f16;
typedef _Float16 f16x8 __attribute__((ext_vector_type(8)));
typedef float    f32x4 __attribute__((ext_vector_type(4)));
typedef unsigned short u16;
typedef unsigned int   u32;
typedef u16 us8 __attribute__((ext_vector_type(8)));
typedef u16 us4 __attribute__((ext_vector_type(4)));

#define MFMA16(a, b, c) __builtin_amdgcn_mfma_f32_16x16x32_f16((a), (b), (c), 0, 0, 0)

__device__ __forceinline__ void gload_lds16(const void* g, void* l) {
    __builtin_amdgcn_global_load_lds((const __attribute__((address_space(1))) void*)g,
                                     (__attribute__((address_space(3))) void*)l, 16, 0, 0);
}

// ---------------- cast f32->f16 (weights only) -----------------------------------
__global__ void castk(const float* __restrict__ src, f16* __restrict__ dst, int n8) {
    int i = blockIdx.x * 256 + threadIdx.x;
    if (i >= n8) return;
    const float4* s = (const float4*)src + (size_t)i * 2;
    float4 a = s[0], b = s[1];
    union { f16 h[8]; us8 v; } o;
    o.h[0] = (f16)a.x; o.h[1] = (f16)a.y; o.h[2] = (f16)a.z; o.h[3] = (f16)a.w;
    o.h[4] = (f16)b.x; o.h[5] = (f16)b.y; o.h[6] = (f16)b.z; o.h[7] = (f16)b.w;
    *(us8*)&dst[(size_t)i * 8] = o.v;
}

// ---------------- prep: O f32 -> Of16 (straight) + OT (transposed), one O read ---
__global__ void prep(const float* __restrict__ O, f16* __restrict__ Of16,
                     f16* __restrict__ OT) {
    __shared__ f16 tbuf[64][68];
    int bid = blockIdx.x;
    int b = bid >> 8, t = bid & 255;
    int s0 = (t & 31) * 64, h0 = (t >> 5) * 64;
    const float* Ob = O + (size_t)b * 2048 * 512;
    f16* Ofb = Of16 + (size_t)b * 2048 * 512;
    f16* OTb = OT + (size_t)b * 512 * 2048;
    int tid = threadIdx.x;
    int rr = tid >> 4, cc = (tid & 15) * 4;
#pragma unroll
    for (int i = 0; i < 4; ++i) {
        int r = rr + 16 * i;
        float4 v = *(const float4*)&Ob[(size_t)(s0 + r) * 512 + h0 + cc];
        union { f16 h[4]; us4 u; } st;
        st.h[0] = (f16)v.x; st.h[1] = (f16)v.y; st.h[2] = (f16)v.z; st.h[3] = (f16)v.w;
        *(us4*)&Ofb[(size_t)(s0 + r) * 512 + h0 + cc] = st.u;
        tbuf[r][cc + 0] = st.h[0]; tbuf[r][cc + 1] = st.h[1];
        tbuf[r][cc + 2] = st.h[2]; tbuf[r][cc + 3] = st.h[3];
    }
    __syncthreads();
#pragma unroll
    for (int i = 0; i < 4; ++i) {
        int hr = rr + 16 * i;
        union { f16 h[4]; us4 v; } pk;
        pk.h[0] = tbuf[cc + 0][hr]; pk.h[1] = tbuf[cc + 1][hr];
        pk.h[2] = tbuf[cc + 2][hr]; pk.h[3] = tbuf[cc + 3][hr];
        *(us4*)&OTb[(size_t)(h0 + hr) * 2048 + s0 + cc] = pk.v;
    }
}

// ---------------- GEMM1: Qf16 = tanh(Of16 * Wf16^T + bias) ----------------------
// Double-buffered global_load_lds staging (m97 pattern): 4 DMA/thread/stage,
// counted vmcnt(4) -> next tile's loads in flight across the compute phase.
__global__ __launch_bounds__(256) void gemm1(const f16* __restrict__ A,
                                             const f16* __restrict__ W,
                                             const float* __restrict__ bias,
                                             f16* __restrict__ Qo) {
    __shared__ f16 lA[2 * 128 * 32];
    __shared__ f16 lB[2 * 128 * 32];
    const int tid = threadIdx.x;
    const int lane = tid & 63, w = tid >> 6;
    const int wm = w >> 1, wn = w & 1;
    const int bm = blockIdx.x >> 2, bn = blockIdx.x & 3;
    const int r0 = bm * 128, c0 = bn * 128;
    const int l15 = lane & 15, g = lane >> 4;
    f32x4 acc[4][4] = {};

    auto STAGE = [&](int buf, int k0) {
        f16* dA = lA + buf * 4096;
        f16* dB = lB + buf * 4096;
#pragma unroll
        for (int i = 0; i < 2; ++i) {
            int slot = i * 256 + tid;
            int row = slot >> 2, oct = slot & 3;
            int soct = oct ^ (row & 3);
            gload_lds16(&A[(size_t)(r0 + row) * 512 + k0 + soct * 8], &dA[slot * 8]);
            gload_lds16(&W[(size_t)(c0 + row) * 512 + k0 + soct * 8], &dB[slot * 8]);
        }
    };

    STAGE(0, 0);
    for (int kt = 0; kt < 16; ++kt) {
        const int cur = kt & 1;
        if (kt < 15) {
            STAGE(cur ^ 1, (kt + 1) * 32);
            asm volatile("s_waitcnt vmcnt(4)" ::: "memory");  // tile kt landed
        } else {
            asm volatile("s_waitcnt vmcnt(0)" ::: "memory");
        }
        __builtin_amdgcn_s_barrier();

        const f16* cA = lA + cur * 4096;
        const f16* cB = lB + cur * 4096;
        f16x8 af[4], bf[4];
#pragma unroll
        for (int mf = 0; mf < 4; ++mf) {
            int row = 64 * wm + 16 * mf + l15;
            int oct = g ^ (row & 3);
            af[mf] = *(const f16x8*)&cA[(row * 4 + oct) * 8];
        }
#pragma unroll
        for (int nf = 0; nf < 4; ++nf) {
            int row = 64 * wn + 16 * nf + l15;
            int oct = g ^ (row & 3);
            bf[nf] = *(const f16x8*)&cB[(row * 4 + oct) * 8];
        }
#pragma unroll
        for (int mf = 0; mf < 4; ++mf)
#pragma unroll
            for (int nf = 0; nf < 4; ++nf)
                acc[mf][nf] = MFMA16(af[mf], bf[nf], acc[mf][nf]);

        asm volatile("s_waitcnt lgkmcnt(0)" ::: "memory");
        __builtin_amdgcn_s_barrier();   // buffer [cur] reusable for kt+2
    }
    float bv[4];
#pragma unroll
    for (int nf = 0; nf < 4; ++nf) bv[nf] = bias[c0 + 64 * wn + 16 * nf + l15];
#pragma unroll
    for (int mf = 0; mf < 4; ++mf) {
#pragma unroll
        for (int nf = 0; nf < 4; ++nf) {
#pragma unroll
            for (int r = 0; r < 4; ++r) {
                float y = tanhf(acc[mf][nf][r] + bv[nf]);
                int row = r0 + 64 * wm + 16 * mf + 4 * g + r;
                int col = c0 + 64 * wn + 16 * nf + l15;
                Qo[(size_t)row * 512 + col] = (f16)y;
            }
        }
    }
}

// ---------------- fused attention, t-split + double-buffered pipeline ------------
// (R10/R12-verified kernel, byte-for-byte: 134 us, VGPR 128 + 128 AGPR, no spill.)
__global__ __launch_bounds__(512, 2) void attn(const f16* __restrict__ Qf,
                                               const f16* __restrict__ Of,
                                               const f16* __restrict__ OfT,
                                               float* __restrict__ P0,
                                               f16* __restrict__ P1,
                                               float* __restrict__ ML) {
    extern __shared__ __align__(16) char smem[];  // 131072
    const int tid = threadIdx.x;
    const int lane = tid & 63, w = tid >> 6;
    const int l15 = lane & 15, g = lane >> 4;
    const int b = blockIdx.x & 7, tt = (blockIdx.x >> 3) & 1, qt = blockIdx.x >> 4;
    const int q0 = qt * 128;
    const int tb = tt * 1024;
    const f16* Ob  = Of  + (size_t)b * 2048 * 512;
    const f16* OTb = OfT + (size_t)b * 512 * 2048;

    f16x8 qf[16];
    const f16* qrow = Qf + ((size_t)b * 2048 + q0 + 16 * w + l15) * 512;
#pragma unroll
    for (int ks = 0; ks < 16; ++ks) qf[ks] = *(const f16x8*)&qrow[ks * 32 + g * 8];

    float m = -INFINITY, lsum = 0.f;
    f32x4 acc[32] = {};

    const int addrA = 4 * (32 * (g & 1) + l15);
    const int addrB = addrA + 64;
    const int kx = (l15 & 3) ^ ((l15 >> 2) & 3);
    const int go = g ^ kx;

    auto STAGE_K = [&](int buf, int t0) {
        f16* dst = (f16*)(smem + buf * 32768);
#pragma unroll
        for (int i = 0; i < 4; ++i) {
            int slot = i * 512 + tid;
            int t = slot >> 6, oct = slot & 63;
            gload_lds16(&Ob[(size_t)(t0 + t) * 512 + 8 * (oct ^ (t & 7))], &dst[slot * 8]);
        }
    };
    auto STAGE_V = [&](int buf, int t0) {
        f16* dst = (f16*)(smem + 65536 + buf * 32768);
#pragma unroll
        for (int i = 0; i < 4; ++i) {
            int slot = i * 512 + tid;
            int h = slot >> 2, gr = slot & 3;
            int key = (h & 3) ^ ((h >> 2) & 3);
            gload_lds16(&OTb[(size_t)h * 2048 + t0 + 8 * (gr ^ key)], &dst[slot * 8]);
        }
    };

    STAGE_K(0, tb);
    STAGE_V(0, tb);

    for (int kt = 0; kt < 32; ++kt) {
        const int cur = kt & 1;
        const f16* lK = (const f16*)(smem + cur * 32768);
        const f16* lV = (const f16*)(smem + 65536 + cur * 32768);

        if (kt < 31) {
            STAGE_K(cur ^ 1, tb + (kt + 1) * 32);
            STAGE_V(cur ^ 1, tb + (kt + 1) * 32);
            asm volatile("s_waitcnt vmcnt(8)" ::: "memory");
        } else {
            asm volatile("s_waitcnt vmcnt(0)" ::: "memory");
        }
        __builtin_amdgcn_s_barrier();

        f32x4 sa[2] = {};
#pragma unroll
        for (int ks = 0; ks < 16; ++ks) {
#pragma unroll
            for (int mf = 0; mf < 2; ++mf) {
                int t = 16 * mf + l15;
                int oct = (4 * ks + g) ^ (t & 7);
                f16x8 kf = *(const f16x8*)&lK[(t * 64 + oct) * 8];
                sa[mf] = MFMA16(kf, qf[ks], sa[mf]);
            }
        }

        float tmax = -INFINITY;
#pragma unroll
        for (int mf = 0; mf < 2; ++mf)
#pragma unroll
            for (int r = 0; r < 4; ++r) tmax = fmaxf(tmax, sa[mf][r]);
        tmax = fmaxf(tmax, __shfl_xor(tmax, 16));
        tmax = fmaxf(tmax, __shfl_xor(tmax, 32));
        if (__any(tmax > m + 8.0f)) {
            float mnew = fmaxf(m, tmax);
            float corr = __expf(m - mnew);
            m = mnew;
            lsum *= corr;
#pragma unroll
            for (int hf = 0; hf < 32; ++hf) acc[hf] *= corr;
        }
        float p[2][4];
        float ps = 0.f;
#pragma unroll
        for (int mf = 0; mf < 2; ++mf)
#pragma unroll
            for (int r = 0; r < 4; ++r) { p[mf][r] = __expf(sa[mf][r] - m); ps += p[mf][r]; }
        ps += __shfl_xor(ps, 16);
        ps += __shfl_xor(ps, 32);
        lsum += ps;

        u32 Wd[2][2];
#pragma unroll
        for (int mf = 0; mf < 2; ++mf)
#pragma unroll
            for (int c = 0; c < 2; ++c) {
                union { f16 h[2]; u32 u; } x;
                x.h[0] = (f16)p[mf][2 * c]; x.h[1] = (f16)p[mf][2 * c + 1];
                Wd[mf][c] = x.u;
            }
        u32 word[4];
#pragma unroll
        for (int pp = 0; pp < 4; ++pp) {
            int adr = (pp >> 1) ? addrB : addrA;
            int w0 = __builtin_amdgcn_ds_bpermute(adr, (int)Wd[0][pp & 1]);
            int w1 = __builtin_amdgcn_ds_bpermute(adr, (int)Wd[1][pp & 1]);
            word[pp] = (lane >= 32) ? (u32)w1 : (u32)w0;
        }
        union { u32 u[4]; f16x8 v; } pkk;
        pkk.u[0] = word[0]; pkk.u[1] = word[1]; pkk.u[2] = word[2]; pkk.u[3] = word[3];
        f16x8 pfrag = pkk.v;

#pragma unroll
        for (int hf = 0; hf < 32; ++hf) {
            int h = 16 * hf + l15;
            f16x8 vf = *(const f16x8*)&lV[(h * 4 + go) * 8];
            acc[hf] = MFMA16(vf, pfrag, acc[hf]);
        }

        asm volatile("s_waitcnt lgkmcnt(0)" ::: "memory");
        __builtin_amdgcn_s_barrier();
    }

    const size_t row = (size_t)b * 2048 + q0 + 16 * w + l15;
    if (g == 0) {
        ML[(tt * 16384 + row) * 2 + 0] = m;
        ML[(tt * 16384 + row) * 2 + 1] = lsum;
    }
    if (tt == 0) {
#pragma unroll
        for (int hf = 0; hf < 32; ++hf) {
            float4 o;
            o.x = acc[hf][0]; o.y = acc[hf][1];
            o.z = acc[hf][2]; o.w = acc[hf][3];
            *(float4*)&P0[row * 512 + 16 * hf + 4 * g] = o;
        }
    } else {
        float inv = 1.0f / lsum;
#pragma unroll
        for (int hf = 0; hf < 32; ++hf) {
            union { f16 h[4]; us4 v; } pk;
            pk.h[0] = (f16)(acc[hf][0] * inv); pk.h[1] = (f16)(acc[hf][1] * inv);
            pk.h[2] = (f16)(acc[hf][2] * inv); pk.h[3] = (f16)(acc[hf][3] * inv);
            *(us4*)&P1[row * 512 + 16 * hf + 4 * g] = pk.v;
        }
    }
}

// ---------------- merge: out = (e0*P0 + e1*l1*P1n) / (e0*l0 + e1*l1) -------------
__global__ __launch_bounds__(256) void merge_k(float* __restrict__ P0,
                                               const f16* __restrict__ P1,
                                               const float* __restrict__ ML) {
    const int tid = threadIdx.x;
    const size_t row = (size_t)blockIdx.x * 8 + (tid >> 5);
    const int c = (tid & 31) * 16;
    float m0 = ML[row * 2 + 0], l0 = ML[row * 2 + 1];
    float m1 = ML[(16384 + row) * 2 + 0], l1 = ML[(16384 + row) * 2 + 1];
    float M = fmaxf(m0, m1);
    float e0 = __expf(m0 - M), e1 = __expf(m1 - M);
    float w1 = e1 * l1;
    float inv = 1.0f / (e0 * l0 + w1);
    float a0 = e0 * inv, a1 = w1 * inv;
#pragma unroll
    for (int j = 0; j < 4; ++j) {
        size_t off = row * 512 + c + 4 * j;
        float4 v0 = *(const float4*)&P0[off];
        us4 v1u = *(const us4*)&P1[off];
        const f16* v1 = (const f16*)&v1u;
        float4 o;
        o.x = a0 * v0.x + a1 * (float)v1[0];
        o.y = a0 * v0.y + a1 * (float)v1[1];
        o.z = a0 * v0.z + a1 * (float)v1[2];
        o.w = a0 * v0.w + a1 * (float)v1[3];
        *(float4*)&P0[off] = o;
    }
}

extern "C" void kernel_launch(void* const* d_in, const int* in_sizes, int n_in,
                              void* d_out, int out_size, void* d_ws, size_t ws_size,
                              hipStream_t stream) {
    const float* O  = (const float*)d_in[0];
    const float* Ww = (const float*)d_in[1];
    const float* Wb = (const float*)d_in[2];
    float* Out = (float*)d_out;
    char* ws = (char*)d_ws;
    f16* Of16 = (f16*)ws;                           // 16 MB
    f16* OT   = (f16*)(ws + ((size_t)16 << 20));    // 16 MB
    f16* Qf   = (f16*)(ws + ((size_t)32 << 20));    // 16 MB
    f16* Wf   = (f16*)(ws + ((size_t)48 << 20));    // 512 KB
    f16* P1   = (f16*)(ws + ((size_t)49 << 20));    // 16 MB (normalized f16 partial)
    float* ML = (float*)(ws + ((size_t)65 << 20));  // 512 KB (m, lsum per row per tt)

    hipFuncSetAttribute((const void*)attn, hipFuncAttributeMaxDynamicSharedMemorySize, 131072);

    prep<<<2048, 256, 0, stream>>>(O, Of16, OT);
    castk<<<128, 256, 0, stream>>>(Ww, Wf, 32768);
    gemm1<<<512, 256, 0, stream>>>(Of16, Wf, Wb, Qf);
    attn<<<256, 512, 131072, stream>>>(Qf, Of16, OT, Out, P1, ML);
    merge_k<<<2048, 256, 0, stream>>>(Out, P1, ML);
}